// Round 16
// baseline (809.635 us; speedup 1.0000x reference)
//
#include <hip/hip_runtime.h>

typedef float f32x4 __attribute__((ext_vector_type(4)));
typedef float f32x2 __attribute__((ext_vector_type(2)));
typedef short short8 __attribute__((ext_vector_type(8)));

#define NN 4096
#define HB 32               // half batch
#define SROW 2048           // state f32 per node row (x0 only), 1<<11
#define IROW 64             // input f32 per node row (x0 only), 1<<6
#define SLVL 8388608ull     // f32 spacing per state level
#define ILVL 262144ull      // f32 spacing per input level
#define KP 352              // padded K (330 real)
#define KSTEPS 11
#define NPB 8               // nodes per mm block (grid 512 = 2 blocks/CU)

__device__ __forceinline__ ushort f2bf(float f){ uint i = __float_as_uint(f); return (ushort)((i + 0x7fffu + ((i >> 16) & 1u)) >> 16); }
__device__ __forceinline__ float bf2f(ushort u){ return __uint_as_float((uint)u << 16); }
__device__ __forceinline__ float lo_f(uint w){ return __uint_as_float(w << 16); }
__device__ __forceinline__ float hi_f(uint w){ return __uint_as_float(w & 0xffff0000u); }
__device__ __forceinline__ uint pkhi2(float a, float b){ return (uint)f2bf(a) | ((uint)f2bf(b) << 16); }
__device__ __forceinline__ float sigm(float x){ return 1.0f / (1.0f + __expf(-x)); }
__device__ __forceinline__ float tanh_fast(float x){
    x = fminf(20.0f, fmaxf(-20.0f, x));
    float t = __expf(-2.0f * x);
    return (1.0f - t) / (1.0f + t);
}
__device__ __forceinline__ f32x4 fma4(float v, f32x4 x, f32x4 a){
    a.x = fmaf(v, x.x, a.x); a.y = fmaf(v, x.y, a.y);
    a.z = fmaf(v, x.z, a.z); a.w = fmaf(v, x.w, a.w);
    return a;
}
__device__ __forceinline__ f32x4 fma4p(float v, uint2 u, f32x4 a){
    a.x = fmaf(v, lo_f(u.x), a.x); a.y = fmaf(v, hi_f(u.x), a.y);
    a.z = fmaf(v, lo_f(u.y), a.z); a.w = fmaf(v, hi_f(u.y), a.w);
    return a;
}

// ---------------- zero scratch (cnt+fill), graph-capture-safe ---------------
__global__ void zero_k(int* __restrict__ p){ p[blockIdx.x * 256 + threadIdx.x] = 0; }

// ------- weight transform: Wt_hi/lo[o][k], k = m*66+f, bf16 hi/lo split -----
__global__ void wtbuild_k(const float* __restrict__ Wru, const float* __restrict__ Wc,
                          ushort* __restrict__ ru_hi, ushort* __restrict__ ru_lo,
                          ushort* __restrict__ c_hi,  ushort* __restrict__ c_lo)
{
    int idx = blockIdx.x * 256 + threadIdx.x;   // 192*352 exact
    float w = 0.0f;
    if (idx < 128 * KP) {
        int o = idx / KP, k = idx - o * KP;
        if (k < 330) { int m = k / 66, f = k - m * 66; w = Wru[(size_t)(f * 5 + m) * 128 + o]; }
        ushort hi = f2bf(w);
        ushort lo = f2bf(w - bf2f(hi));
        ru_hi[(size_t)o * KP + k] = hi;
        ru_lo[(size_t)o * KP + k] = lo;
    } else {
        int j = idx - 128 * KP;
        int o = j / KP, k = j - o * KP;
        if (k < 330) { int m = k / 66, f = k - m * 66; w = Wc[(size_t)(f * 5 + m) * 64 + o]; }
        ushort hi = f2bf(w);
        ushort lo = f2bf(w - bf2f(hi));
        c_hi[(size_t)o * KP + k] = hi;
        c_lo[(size_t)o * KP + k] = lo;
    }
}

// ---------------- CSR build ------------------------------------------------
__global__ void count_k(const int* __restrict__ rows, int* __restrict__ cnt)
{
    int i = blockIdx.x * 256 + threadIdx.x;     // 2*65536 exact
    int s = i >> 16;
    atomicAdd(&cnt[(s << 12) + rows[i]], 1);
}

__global__ __launch_bounds__(1024) void scan_k(const int* __restrict__ cnt, int* __restrict__ rp)
{
    int s = blockIdx.x;
    const int* c = cnt + (s << 12);
    int* r = rp + s * 4097;
    __shared__ int sd[1024];
    int tid = threadIdx.x;
    int i0 = tid * 4;
    int a0 = c[i0], a1 = c[i0 + 1], a2 = c[i0 + 2], a3 = c[i0 + 3];
    sd[tid] = a0 + a1 + a2 + a3;
    __syncthreads();
    for (int off = 1; off < 1024; off <<= 1) {
        int v = (tid >= off) ? sd[tid - off] : 0;
        __syncthreads();
        sd[tid] += v;
        __syncthreads();
    }
    int base = tid ? sd[tid - 1] : 0;
    r[i0] = base; r[i0 + 1] = base + a0; r[i0 + 2] = base + a0 + a1; r[i0 + 3] = base + a0 + a1 + a2;
    if (tid == 1023) r[4096] = sd[1023];
}

// scatter into packed (col, val) CSR stream
__global__ void scatter_k(const int* __restrict__ rows, const int* __restrict__ cols,
                          const float* __restrict__ vals, const int* __restrict__ rp,
                          int* __restrict__ fill, int2* __restrict__ pcv)
{
    int i = blockIdx.x * 256 + threadIdx.x;     // 2*65536 exact
    int s = i >> 16;
    int r = rows[i];
    int pos = rp[s * 4097 + r] + atomicAdd(&fill[(s << 12) + r], 1);
    int2 e; e.x = cols[i]; e.y = __float_as_int(vals[i]);
    pcv[(s << 16) + pos] = e;
}

// ---------------- x0 build: input part (f32) --------------------------------
__global__ void x0i_k(const float* __restrict__ in, float* __restrict__ x0i, int h)
{
    int i = blockIdx.x * 256 + threadIdx.x;     // 4096*32 exact
    int n = i >> 5, bl = i & 31;
    const f32x2 v = *(const f32x2*)(in + (size_t)(h * HB + bl) * 8192 + n * 2);
    *(f32x2*)(x0i + (size_t)n * IROW + bl * 2) = v;
}

// ---------------- SpMM v12: uniform edge loads, templated mode --------------
// Edge (col,val) fetched by a group-uniform 8B load (hardware broadcast, 1
// transaction, pipelines with gathers) instead of register-stage + shfl.
// MODE 0: src f32, dst packed bf16. MODE 1: src packed bf16, prev f32,
// dst packed bf16.
template<int MODE>
__global__ __launch_bounds__(256) void spmm_k(
    const float* __restrict__ ss0, const float* __restrict__ si0,
    const float* __restrict__ ss1, const float* __restrict__ si1,
    float* __restrict__ ds0, float* __restrict__ di0,
    float* __restrict__ ds1, float* __restrict__ di1,
    const float* __restrict__ ps, const float* __restrict__ pi,
    const int* __restrict__ rp, const int2* __restrict__ pcv,
    int hxsm, int hxpm)
{
    const int b = blockIdx.x;
    const int tid = threadIdx.x;
    int s, sub = 0, rowgrp;
    bool is_main;
    if (MODE == 0) {
        s = blockIdx.y;
        if (b < 8192) {
            is_main = true;
            const int j = b >> 3;
            sub = (b & 7) * 2 + (j >> 9);
            rowgrp = j & 511;
        } else {
            is_main = false;
            rowgrp = b - 8192;
        }
    } else {
        if (b < 16384) {
            is_main = true;
            const int phase = b >> 12;
            s = phase >> 1;
            sub = (b & 7) * 2 + (phase & 1);
            rowgrp = (b >> 3) & 511;
        } else {
            is_main = false;
            const int j2 = b - 16384;
            s = j2 >> 8;
            rowgrp = j2 & 255;
        }
    }
    const int2* __restrict__ es = pcv + (s << 16);
    const int* __restrict__ rps = rp + s * 4097;
    const int wave = tid >> 6, lane = tid & 63;

    uint* dstu;
    const float* xf = nullptr;      // MODE-0 gather base (f32)
    const uint*  xu = nullptr;      // MODE-1 gather base (packed)
    const float* pb;
    int cshf = 0, cshu = 0, psh, r, drow;
    if (is_main) {
        const int gl = lane & 31;
        r = rowgrp * 8 + wave * 2 + ((lane >> 5) & 1);
        const int q = sub * 32 + gl;
        if (MODE == 0) {
            const float* xsrc = s ? ss1 : ss0;
            if (hxsm) { xf = xsrc + (size_t)(q >> 4) * 262144 + (q & 15) * 4; cshf = 6; }
            else      { xf = xsrc + q * 4;                                    cshf = 11; }
        } else {
            xu = (const uint*)(s ? ss1 : ss0) + q * 2; cshu = 10;
        }
        if (hxpm) { pb = ps + (size_t)(q >> 4) * 262144 + (q & 15) * 4; psh = 6; }
        else      { pb = ps + q * 4;                                    psh = 11; }
        dstu = (uint*)(s ? ds1 : ds0) + q * 2;
        drow = 1024;
    } else {
        const int gl = lane & 15;
        r = rowgrp * 16 + wave * 4 + (lane >> 4);
        if (MODE == 0) { xf = (s ? si1 : si0) + gl * 4;               cshf = 6; }
        else           { xu = (const uint*)(s ? si1 : si0) + gl * 2;  cshu = 5; }
        pb = pi + gl * 4; psh = 6;
        dstu = (uint*)(s ? di1 : di0) + gl * 2;
        drow = 32;
    }
    const int pS = rps[r];
    const int cnt = rps[r + 1] - pS;
    const int2* __restrict__ ep = es + pS;

    f32x4 a0 = {0,0,0,0}, a1 = {0,0,0,0}, a2 = {0,0,0,0}, a3 = {0,0,0,0};
    int e = 0;
    if (MODE == 0) {
        for (; e + 8 <= cnt; e += 8) {
            const int2 E0 = ep[e+0], E1 = ep[e+1], E2 = ep[e+2], E3 = ep[e+3];
            const int2 E4 = ep[e+4], E5 = ep[e+5], E6 = ep[e+6], E7 = ep[e+7];
            const f32x4 x0v = *(const f32x4*)(xf + ((size_t)E0.x << cshf));
            const f32x4 x1v = *(const f32x4*)(xf + ((size_t)E1.x << cshf));
            const f32x4 x2v = *(const f32x4*)(xf + ((size_t)E2.x << cshf));
            const f32x4 x3v = *(const f32x4*)(xf + ((size_t)E3.x << cshf));
            const f32x4 x4v = *(const f32x4*)(xf + ((size_t)E4.x << cshf));
            const f32x4 x5v = *(const f32x4*)(xf + ((size_t)E5.x << cshf));
            const f32x4 x6v = *(const f32x4*)(xf + ((size_t)E6.x << cshf));
            const f32x4 x7v = *(const f32x4*)(xf + ((size_t)E7.x << cshf));
            a0 = fma4(__int_as_float(E0.y), x0v, a0);
            a1 = fma4(__int_as_float(E1.y), x1v, a1);
            a2 = fma4(__int_as_float(E2.y), x2v, a2);
            a3 = fma4(__int_as_float(E3.y), x3v, a3);
            a0 = fma4(__int_as_float(E4.y), x4v, a0);
            a1 = fma4(__int_as_float(E5.y), x5v, a1);
            a2 = fma4(__int_as_float(E6.y), x6v, a2);
            a3 = fma4(__int_as_float(E7.y), x7v, a3);
        }
        for (; e + 2 <= cnt; e += 2) {
            const int2 E0 = ep[e], E1 = ep[e+1];
            const f32x4 x0v = *(const f32x4*)(xf + ((size_t)E0.x << cshf));
            const f32x4 x1v = *(const f32x4*)(xf + ((size_t)E1.x << cshf));
            a0 = fma4(__int_as_float(E0.y), x0v, a0);
            a1 = fma4(__int_as_float(E1.y), x1v, a1);
        }
        if (e < cnt) {
            const int2 E0 = ep[e];
            const f32x4 x0v = *(const f32x4*)(xf + ((size_t)E0.x << cshf));
            a0 = fma4(__int_as_float(E0.y), x0v, a0);
        }
    } else {
        for (; e + 8 <= cnt; e += 8) {
            const int2 E0 = ep[e+0], E1 = ep[e+1], E2 = ep[e+2], E3 = ep[e+3];
            const int2 E4 = ep[e+4], E5 = ep[e+5], E6 = ep[e+6], E7 = ep[e+7];
            const uint2 u0 = *(const uint2*)(xu + ((size_t)E0.x << cshu));
            const uint2 u1 = *(const uint2*)(xu + ((size_t)E1.x << cshu));
            const uint2 u2 = *(const uint2*)(xu + ((size_t)E2.x << cshu));
            const uint2 u3 = *(const uint2*)(xu + ((size_t)E3.x << cshu));
            const uint2 u4 = *(const uint2*)(xu + ((size_t)E4.x << cshu));
            const uint2 u5 = *(const uint2*)(xu + ((size_t)E5.x << cshu));
            const uint2 u6 = *(const uint2*)(xu + ((size_t)E6.x << cshu));
            const uint2 u7 = *(const uint2*)(xu + ((size_t)E7.x << cshu));
            a0 = fma4p(__int_as_float(E0.y), u0, a0);
            a1 = fma4p(__int_as_float(E1.y), u1, a1);
            a2 = fma4p(__int_as_float(E2.y), u2, a2);
            a3 = fma4p(__int_as_float(E3.y), u3, a3);
            a0 = fma4p(__int_as_float(E4.y), u4, a0);
            a1 = fma4p(__int_as_float(E5.y), u5, a1);
            a2 = fma4p(__int_as_float(E6.y), u6, a2);
            a3 = fma4p(__int_as_float(E7.y), u7, a3);
        }
        for (; e + 2 <= cnt; e += 2) {
            const int2 E0 = ep[e], E1 = ep[e+1];
            const uint2 u0 = *(const uint2*)(xu + ((size_t)E0.x << cshu));
            const uint2 u1 = *(const uint2*)(xu + ((size_t)E1.x << cshu));
            a0 = fma4p(__int_as_float(E0.y), u0, a0);
            a1 = fma4p(__int_as_float(E1.y), u1, a1);
        }
        if (e < cnt) {
            const int2 E0 = ep[e];
            const uint2 u0 = *(const uint2*)(xu + ((size_t)E0.x << cshu));
            a0 = fma4p(__int_as_float(E0.y), u0, a0);
        }
    }
    f32x4 R;
    R.x = (a0.x + a1.x) + (a2.x + a3.x);
    R.y = (a0.y + a1.y) + (a2.y + a3.y);
    R.z = (a0.z + a1.z) + (a2.z + a3.z);
    R.w = (a0.w + a1.w) + (a2.w + a3.w);

    if (MODE) {
        const f32x4 pv = *(const f32x4*)(pb + ((size_t)r << psh));
        R.x = 2.0f * R.x - pv.x; R.y = 2.0f * R.y - pv.y;
        R.z = 2.0f * R.z - pv.z; R.w = 2.0f * R.w - pv.w;
    }
    uint2 o2;
    o2.x = pkhi2(R.x, R.y); o2.y = pkhi2(R.z, R.w);
    *(uint2*)(dstu + (size_t)r * drow) = o2;
}

// ------ mm staging: m=0 f32 -> pack; m=1..4 pre-packed copy -----------------
template<int NT>
__device__ __forceinline__ void stage_hi(const float* __restrict__ xs, const float* __restrict__ xi,
                                         const float* __restrict__ m0s, int m0hx,
                                         int n, int tid, uint* __restrict__ Bhi)
{
    for (int i = tid; i < 480; i += NT) {       // zero K-pad words 165..179 per b-row
        int bl = i / 15, t = i - bl * 15;
        Bhi[bl * 180 + 165 + t] = 0u;
    }
    for (int i = tid; i < 2560; i += NT) {      // state: 5 m x 32 bl x 16 quads
        int m = i >> 9, rem = i & 511, bl = rem >> 4, fq = rem & 15;
        const int base = bl * 180 + m * 33 + 1 + fq * 2;
        if (m == 0) {
            const float* p = m0hx ? m0s + (size_t)bl * 262144 + (size_t)n * 64 + fq * 4
                                  : m0s + (size_t)n * SROW + bl * 64 + fq * 4;
            const f32x4 v = *(const f32x4*)p;
            Bhi[base]     = pkhi2(v.x, v.y);
            Bhi[base + 1] = pkhi2(v.z, v.w);
        } else {
            const uint* xp = (const uint*)(xs + (size_t)m * SLVL);
            const uint2 u = *(const uint2*)(xp + (size_t)n * 1024 + bl * 32 + fq * 2);
            Bhi[base]     = u.x;
            Bhi[base + 1] = u.y;
        }
    }
    for (int i = tid; i < 160; i += NT) {       // input: 5 m x 32 bl
        int m = i >> 5, bl = i & 31;
        if (m == 0) {
            const f32x2 v = *(const f32x2*)(xi + (size_t)n * IROW + bl * 2);
            Bhi[bl * 180] = pkhi2(v.x, v.y);
        } else {
            const uint* xp = (const uint*)(xi + (size_t)m * ILVL);
            Bhi[bl * 180 + m * 33] = xp[(size_t)n * 32 + bl];
        }
    }
}

#define MFMA(a, b, c) __builtin_amdgcn_mfma_f32_16x16x32_bf16(a, b, c, 0, 0, 0)

// -------- gconv1 matmul (round-12 proven config): 8 nodes/block, 8 waves ----
__global__ __launch_bounds__(512, 4) void mm_ru_k(const float* __restrict__ xs, const float* __restrict__ xi,
                                                  const ushort* __restrict__ whi, const ushort* __restrict__ wlo,
                                                  const float* __restrict__ bru, const float* __restrict__ hx,
                                                  float* __restrict__ uout, float* __restrict__ xs0s, int h)
{
    const int tid = threadIdx.x;
    const int lane = tid & 63, wave = tid >> 6;
    __shared__ uint Bbuf[2][5760];
    const int n0 = blockIdx.x * NPB;
    const float* hxs = hx + (size_t)h * HB * 262144;

    const int ob = wave * 16 + (lane & 15);
    const int ksub = (lane >> 4) * 8;
    const int brow = lane & 15;
    short8 Ah[KSTEPS], Al[KSTEPS];
    #pragma unroll
    for (int ks = 0; ks < KSTEPS; ++ks) {
        Ah[ks] = *(const short8*)(whi + (size_t)ob * KP + ks * 32 + ksub);
        Al[ks] = *(const short8*)(wlo + (size_t)ob * KP + ks * 32 + ksub);
    }
    const int g = lane >> 4, bcol = lane & 15;
    const int o = wave * 16 + g * 4;
    const float bb0 = bru[o], bb1 = bru[o + 1], bb2 = bru[o + 2], bb3 = bru[o + 3];

    stage_hi<512>(xs, xi, hxs, 1, n0, tid, Bbuf[0]);

    for (int i = 0; i < NPB; ++i) {
        __syncthreads();
        if (i + 1 < NPB)
            stage_hi<512>(xs, xi, hxs, 1, n0 + i + 1, tid, Bbuf[(i + 1) & 1]);
        const ushort* BH = (const ushort*)Bbuf[i & 1];
        const int n = n0 + i;
        f32x4 acc[2] = {};
        #pragma unroll
        for (int ks = 0; ks < KSTEPS; ++ks) {
            const int ko = ks * 32 + ksub;
            short8 Bh0 = *(const short8*)(BH + brow * 360 + ko);
            short8 Bh1 = *(const short8*)(BH + (16 + brow) * 360 + ko);
            acc[0] = MFMA(Ah[ks], Bh0, acc[0]);
            acc[1] = MFMA(Ah[ks], Bh1, acc[1]);
            acc[0] = MFMA(Al[ks], Bh0, acc[0]);
            acc[1] = MFMA(Al[ks], Bh1, acc[1]);
        }
        #pragma unroll
        for (int bt = 0; bt < 2; ++bt) {
            const int bl = bt * 16 + bcol;
            float s0 = sigm(acc[bt][0] + bb0);
            float s1 = sigm(acc[bt][1] + bb1);
            float s2 = sigm(acc[bt][2] + bb2);
            float s3 = sigm(acc[bt][3] + bb3);
            if (wave < 4) {     // r-part: r*hx -> x0 state
                const f32x4 hxv = *(const f32x4*)(hx + (size_t)(h * HB + bl) * 262144 + (size_t)n * 64 + o);
                f32x4 rv;
                rv[0] = s0 * hxv[0]; rv[1] = s1 * hxv[1];
                rv[2] = s2 * hxv[2]; rv[3] = s3 * hxv[3];
                *(f32x4*)(xs0s + (size_t)n * SROW + bl * 64 + o) = rv;
            } else {            // u-part -> d_out (temporary storage)
                f32x4 uv = {s0, s1, s2, s3};
                *(f32x4*)(uout + (size_t)(h * HB + bl) * 262144 + (size_t)n * 64 + (o - 64)) = uv;
            }
        }
    }
}

// -------- gconv2 matmul: 8 nodes/block, 4 waves (round-12 config) -----------
__global__ __launch_bounds__(256, 4) void mm_c_k(const float* __restrict__ xs, const float* __restrict__ xi,
                                                 const ushort* __restrict__ whi, const ushort* __restrict__ wlo,
                                                 const float* __restrict__ bc, const float* __restrict__ hx,
                                                 float* __restrict__ out, int h)
{
    const int tid = threadIdx.x;
    const int lane = tid & 63, wave = tid >> 6;
    __shared__ uint Bbuf[2][5760];
    const int n0 = blockIdx.x * NPB;

    const int ob = wave * 16 + (lane & 15);
    const int ksub = (lane >> 4) * 8;
    const int brow = lane & 15;
    short8 Ah[KSTEPS], Al[KSTEPS];
    #pragma unroll
    for (int ks = 0; ks < KSTEPS; ++ks) {
        Ah[ks] = *(const short8*)(whi + (size_t)ob * KP + ks * 32 + ksub);
        Al[ks] = *(const short8*)(wlo + (size_t)ob * KP + ks * 32 + ksub);
    }
    const int g = lane >> 4, bcol = lane & 15;
    const int o = wave * 16 + g * 4;
    const float bb0 = bc[o], bb1 = bc[o + 1], bb2 = bc[o + 2], bb3 = bc[o + 3];

    stage_hi<256>(xs, xi, xs, 0, n0, tid, Bbuf[0]);

    for (int i = 0; i < NPB; ++i) {
        __syncthreads();
        if (i + 1 < NPB)
            stage_hi<256>(xs, xi, xs, 0, n0 + i + 1, tid, Bbuf[(i + 1) & 1]);
        const ushort* BH = (const ushort*)Bbuf[i & 1];
        const int n = n0 + i;
        f32x4 acc[2] = {};
        #pragma unroll
        for (int ks = 0; ks < KSTEPS; ++ks) {
            const int ko = ks * 32 + ksub;
            short8 Bh0 = *(const short8*)(BH + brow * 360 + ko);
            short8 Bh1 = *(const short8*)(BH + (16 + brow) * 360 + ko);
            acc[0] = MFMA(Ah[ks], Bh0, acc[0]);
            acc[1] = MFMA(Ah[ks], Bh1, acc[1]);
            acc[0] = MFMA(Al[ks], Bh0, acc[0]);
            acc[1] = MFMA(Al[ks], Bh1, acc[1]);
        }
        #pragma unroll
        for (int bt = 0; bt < 2; ++bt) {
            const int bl = bt * 16 + bcol;
            float c0 = tanh_fast(acc[bt][0] + bb0);
            float c1 = tanh_fast(acc[bt][1] + bb1);
            float c2 = tanh_fast(acc[bt][2] + bb2);
            float c3 = tanh_fast(acc[bt][3] + bb3);
            float* p = out + (size_t)(h * HB + bl) * 262144 + (size_t)n * 64 + o;
            const f32x4 hxv = *(const f32x4*)(hx + (size_t)(h * HB + bl) * 262144 + (size_t)n * 64 + o);
            f32x4 uv = *(const f32x4*)p;
            f32x4 ov;
            ov[0] = uv[0] * hxv[0] + (1.0f - uv[0]) * c0;
            ov[1] = uv[1] * hxv[1] + (1.0f - uv[1]) * c1;
            ov[2] = uv[2] * hxv[2] + (1.0f - uv[2]) * c2;
            ov[3] = uv[3] * hxv[3] + (1.0f - uv[3]) * c3;
            *(f32x4*)p = ov;
        }
    }
}

// ---------------------------------------------------------------------------
extern "C" void kernel_launch(void* const* d_in, const int* in_sizes, int n_in,
                              void* d_out, int out_size, void* d_ws, size_t ws_size,
                              hipStream_t stream)
{
    (void)in_sizes; (void)n_in; (void)out_size; (void)ws_size;
    const float* inputs  = (const float*)d_in[0];
    const float* hx      = (const float*)d_in[1];
    const int*   sup_rows= (const int*)d_in[2];
    const int*   sup_cols= (const int*)d_in[3];
    const float* sup_vals= (const float*)d_in[4];
    const float* W_ru    = (const float*)d_in[5];
    const float* b_ru    = (const float*)d_in[6];
    const float* W_c     = (const float*)d_in[7];
    const float* b_c     = (const float*)d_in[8];
    float* out = (float*)d_out;

    char* ws = (char*)d_ws;
    float* xs = (float*)ws;                                 // level 0 f32; levels 1-4 packed bf16
    float* xi = xs + 5ull * SLVL;
    size_t off = (5ull * SLVL + 5ull * ILVL) * 4ull;        // 173,015,040
    ushort* wru_hi = (ushort*)(ws + off); off += 90112;
    ushort* wru_lo = (ushort*)(ws + off); off += 90112;
    ushort* wc_hi  = (ushort*)(ws + off); off += 45056;
    ushort* wc_lo  = (ushort*)(ws + off); off += 45056;
    int* row_ptr   = (int*)(ws + off);    off += 32800;
    int* cntfill   = (int*)(ws + off);    off += 65536;
    int2* pcv      = (int2*)(ws + off);   off += 1048576;   // packed (col,val) CSR

    #define XS(m) (xs + (size_t)(m) * SLVL)
    #define XI(m) (xi + (size_t)(m) * ILVL)
    int* fill = cntfill + 8192;

    zero_k<<<64, 256, 0, stream>>>(cntfill);
    wtbuild_k<<<264, 256, 0, stream>>>(W_ru, W_c, wru_hi, wru_lo, wc_hi, wc_lo);
    count_k<<<512, 256, 0, stream>>>(sup_rows, cntfill);
    scan_k<<<2, 1024, 0, stream>>>(cntfill, row_ptr);
    scatter_k<<<512, 256, 0, stream>>>(sup_rows, sup_cols, sup_vals, row_ptr, fill, pcv);

    for (int h = 0; h < 2; ++h) {
        const float* hxs = hx + (size_t)h * HB * 262144;
        x0i_k<<<512, 256, 0, stream>>>(inputs, XI(0), h);
        // gconv1 diffusion: step1 reads hx in place, writes packed x1/x3;
        // step2 gathers packed, prev = hx (hxpm)
        spmm_k<0><<<dim3(8448, 2), 256, 0, stream>>>(hxs, XI(0), hxs, XI(0),
                                                     XS(1), XI(1), XS(3), XI(3),
                                                     hxs, XI(0), row_ptr, pcv, 1, 0);
        spmm_k<1><<<dim3(16896, 1), 256, 0, stream>>>(XS(1), XI(1), XS(3), XI(3),
                                                      XS(2), XI(2), XS(4), XI(4),
                                                      hxs, XI(0), row_ptr, pcv, 0, 1);
        // gconv1 matmul: u -> out, r*hx -> x0 state part (m0 staged from hx)
        mm_ru_k<<<NN / NPB, 512, 0, stream>>>(xs, xi, wru_hi, wru_lo, b_ru, hx, out, XS(0), h);
        // gconv2 diffusion (x0 = [inputs, r*hx] f32; chain packed)
        spmm_k<0><<<dim3(8448, 2), 256, 0, stream>>>(XS(0), XI(0), XS(0), XI(0),
                                                     XS(1), XI(1), XS(3), XI(3),
                                                     XS(0), XI(0), row_ptr, pcv, 0, 0);
        spmm_k<1><<<dim3(16896, 1), 256, 0, stream>>>(XS(1), XI(1), XS(3), XI(3),
                                                      XS(2), XI(2), XS(4), XI(4),
                                                      XS(0), XI(0), row_ptr, pcv, 0, 0);
        // gconv2 matmul + tanh + final GRU combine
        mm_c_k<<<NN / NPB, 256, 0, stream>>>(xs, xi, wc_hi, wc_lo, b_c, hx, out, h);
    }
    #undef XS
    #undef XI
}

// Round 17
// 700.375 us; speedup vs baseline: 1.1560x; 1.1560x over previous
//
#include <hip/hip_runtime.h>

typedef float f32x4 __attribute__((ext_vector_type(4)));
typedef float f32x2 __attribute__((ext_vector_type(2)));
typedef short short8 __attribute__((ext_vector_type(8)));

#define NN 4096
#define HB 32               // half batch
#define SROW 2048           // state f32 per node row (x0 only), 1<<11
#define IROW 64             // input f32 per node row (x0 only), 1<<6
#define SLVL 8388608ull     // f32 spacing per state level
#define ILVL 262144ull      // f32 spacing per input level
#define KP 352              // padded K (330 real)
#define KSTEPS 11
#define NPB 8               // nodes per mm block (grid 512 = 2 blocks/CU)

__device__ __forceinline__ ushort f2bf(float f){ uint i = __float_as_uint(f); return (ushort)((i + 0x7fffu + ((i >> 16) & 1u)) >> 16); }
__device__ __forceinline__ float bf2f(ushort u){ return __uint_as_float((uint)u << 16); }
__device__ __forceinline__ float lo_f(uint w){ return __uint_as_float(w << 16); }
__device__ __forceinline__ float hi_f(uint w){ return __uint_as_float(w & 0xffff0000u); }
__device__ __forceinline__ uint pkhi2(float a, float b){ return (uint)f2bf(a) | ((uint)f2bf(b) << 16); }
__device__ __forceinline__ float sigm(float x){ return 1.0f / (1.0f + __expf(-x)); }
__device__ __forceinline__ float tanh_fast(float x){
    x = fminf(20.0f, fmaxf(-20.0f, x));
    float t = __expf(-2.0f * x);
    return (1.0f - t) / (1.0f + t);
}
__device__ __forceinline__ f32x4 fma4(float v, f32x4 x, f32x4 a){
    a.x = fmaf(v, x.x, a.x); a.y = fmaf(v, x.y, a.y);
    a.z = fmaf(v, x.z, a.z); a.w = fmaf(v, x.w, a.w);
    return a;
}
__device__ __forceinline__ f32x4 fma4p(float v, uint2 u, f32x4 a){
    a.x = fmaf(v, lo_f(u.x), a.x); a.y = fmaf(v, hi_f(u.x), a.y);
    a.z = fmaf(v, lo_f(u.y), a.z); a.w = fmaf(v, hi_f(u.y), a.w);
    return a;
}

// ---------------- zero scratch (cnt+fill), graph-capture-safe ---------------
__global__ void zero_k(int* __restrict__ p){ p[blockIdx.x * 256 + threadIdx.x] = 0; }

// ------- weight transform: Wt_hi/lo[o][k], k = m*66+f, bf16 hi/lo split -----
__global__ void wtbuild_k(const float* __restrict__ Wru, const float* __restrict__ Wc,
                          ushort* __restrict__ ru_hi, ushort* __restrict__ ru_lo,
                          ushort* __restrict__ c_hi,  ushort* __restrict__ c_lo)
{
    int idx = blockIdx.x * 256 + threadIdx.x;   // 192*352 exact
    float w = 0.0f;
    if (idx < 128 * KP) {
        int o = idx / KP, k = idx - o * KP;
        if (k < 330) { int m = k / 66, f = k - m * 66; w = Wru[(size_t)(f * 5 + m) * 128 + o]; }
        ushort hi = f2bf(w);
        ushort lo = f2bf(w - bf2f(hi));
        ru_hi[(size_t)o * KP + k] = hi;
        ru_lo[(size_t)o * KP + k] = lo;
    } else {
        int j = idx - 128 * KP;
        int o = j / KP, k = j - o * KP;
        if (k < 330) { int m = k / 66, f = k - m * 66; w = Wc[(size_t)(f * 5 + m) * 64 + o]; }
        ushort hi = f2bf(w);
        ushort lo = f2bf(w - bf2f(hi));
        c_hi[(size_t)o * KP + k] = hi;
        c_lo[(size_t)o * KP + k] = lo;
    }
}

// ---------------- CSR build ------------------------------------------------
__global__ void count_k(const int* __restrict__ rows, int* __restrict__ cnt)
{
    int i = blockIdx.x * 256 + threadIdx.x;     // 2*65536 exact
    int s = i >> 16;
    atomicAdd(&cnt[(s << 12) + rows[i]], 1);
}

__global__ __launch_bounds__(1024) void scan_k(const int* __restrict__ cnt, int* __restrict__ rp)
{
    int s = blockIdx.x;
    const int* c = cnt + (s << 12);
    int* r = rp + s * 4097;
    __shared__ int sd[1024];
    int tid = threadIdx.x;
    int i0 = tid * 4;
    int a0 = c[i0], a1 = c[i0 + 1], a2 = c[i0 + 2], a3 = c[i0 + 3];
    sd[tid] = a0 + a1 + a2 + a3;
    __syncthreads();
    for (int off = 1; off < 1024; off <<= 1) {
        int v = (tid >= off) ? sd[tid - off] : 0;
        __syncthreads();
        sd[tid] += v;
        __syncthreads();
    }
    int base = tid ? sd[tid - 1] : 0;
    r[i0] = base; r[i0 + 1] = base + a0; r[i0 + 2] = base + a0 + a1; r[i0 + 3] = base + a0 + a1 + a2;
    if (tid == 1023) r[4096] = sd[1023];
}

// scatter into packed (col, val) CSR stream
__global__ void scatter_k(const int* __restrict__ rows, const int* __restrict__ cols,
                          const float* __restrict__ vals, const int* __restrict__ rp,
                          int* __restrict__ fill, int2* __restrict__ pcv)
{
    int i = blockIdx.x * 256 + threadIdx.x;     // 2*65536 exact
    int s = i >> 16;
    int r = rows[i];
    int pos = rp[s * 4097 + r] + atomicAdd(&fill[(s << 12) + r], 1);
    int2 e; e.x = cols[i]; e.y = __float_as_int(vals[i]);
    pcv[(s << 16) + pos] = e;
}

// ---------------- x0 build: input part (f32) --------------------------------
__global__ void x0i_k(const float* __restrict__ in, float* __restrict__ x0i, int h)
{
    int i = blockIdx.x * 256 + threadIdx.x;     // 4096*32 exact
    int n = i >> 5, bl = i & 31;
    const f32x2 v = *(const f32x2*)(in + (size_t)(h * HB + bl) * 8192 + n * 2);
    *(f32x2*)(x0i + (size_t)n * IROW + bl * 2) = v;
}

// ---------------- SpMM v13: shfl edge broadcast + template MODE -------------
// MODE 0 (step1): src f32 (x0 / hx), dst packed bf16 (x1,x3).
// MODE 1 (step2): src packed bf16, prev f32 (x0/hx), dst packed bf16 (x2,x4).
// Edges: one coalesced 8B/lane load per W-batch, broadcast via shfl (cheap
// VALU on resident regs — r16 showed uniform loads cost +8% latency).
template<int MODE>
__global__ __launch_bounds__(256) void spmm_k(
    const float* __restrict__ ss0, const float* __restrict__ si0,
    const float* __restrict__ ss1, const float* __restrict__ si1,
    float* __restrict__ ds0, float* __restrict__ di0,
    float* __restrict__ ds1, float* __restrict__ di1,
    const float* __restrict__ ps, const float* __restrict__ pi,
    const int* __restrict__ rp, const int2* __restrict__ pcv,
    int hxsm, int hxpm)
{
    const int b = blockIdx.x;
    const int tid = threadIdx.x;
    int s, sub = 0, rowgrp;
    bool is_main;
    if (MODE == 0) {
        s = blockIdx.y;
        if (b < 8192) {
            is_main = true;
            const int j = b >> 3;
            sub = (b & 7) * 2 + (j >> 9);
            rowgrp = j & 511;
        } else {
            is_main = false;
            rowgrp = b - 8192;
        }
    } else {
        if (b < 16384) {
            is_main = true;
            const int phase = b >> 12;
            s = phase >> 1;
            sub = (b & 7) * 2 + (phase & 1);
            rowgrp = (b >> 3) & 511;
        } else {
            is_main = false;
            const int j2 = b - 16384;
            s = j2 >> 8;
            rowgrp = j2 & 255;
        }
    }
    const int2* __restrict__ es = pcv + (s << 16);
    const int* __restrict__ rps = rp + s * 4097;
    const int wave = tid >> 6, lane = tid & 63;

    uint* dstu;
    const float* xf = nullptr;      // MODE-0 gather base (f32)
    const uint*  xu = nullptr;      // MODE-1 gather base (packed)
    const float* pb;
    int cshf = 0, cshu = 0, psh, r, gl, W, drow;
    if (is_main) {
        gl = lane & 31; W = 32;
        r = rowgrp * 8 + wave * 2 + ((lane >> 5) & 1);
        const int q = sub * 32 + gl;
        if (MODE == 0) {
            const float* xsrc = s ? ss1 : ss0;
            if (hxsm) { xf = xsrc + (size_t)(q >> 4) * 262144 + (q & 15) * 4; cshf = 6; }
            else      { xf = xsrc + q * 4;                                    cshf = 11; }
        } else {
            xu = (const uint*)(s ? ss1 : ss0) + q * 2; cshu = 10;
        }
        if (hxpm) { pb = ps + (size_t)(q >> 4) * 262144 + (q & 15) * 4; psh = 6; }
        else      { pb = ps + q * 4;                                    psh = 11; }
        dstu = (uint*)(s ? ds1 : ds0) + q * 2;
        drow = 1024;
    } else {
        gl = lane & 15; W = 16;
        r = rowgrp * 16 + wave * 4 + (lane >> 4);
        if (MODE == 0) { xf = (s ? si1 : si0) + gl * 4;               cshf = 6; }
        else           { xu = (const uint*)(s ? si1 : si0) + gl * 2;  cshu = 5; }
        pb = pi + gl * 4; psh = 6;
        dstu = (uint*)(s ? di1 : di0) + gl * 2;
        drow = 32;
    }
    const int pS = rps[r];
    const int cnt = rps[r + 1] - pS;

    f32x4 a0 = {0,0,0,0}, a1 = {0,0,0,0}, a2 = {0,0,0,0}, a3 = {0,0,0,0};
    for (int b2 = 0; b2 < cnt; b2 += W) {
        const int rem = cnt - b2;
        int2 E; E.x = 0; E.y = 0;
        if (gl < rem) E = es[pS + b2 + gl];
        const int n2 = rem < W ? rem : W;
        int j = 0;
        if (MODE == 0) {
            for (; j + 8 <= n2; j += 8) {
                const int c0 = __shfl(E.x, j + 0, W), c1 = __shfl(E.x, j + 1, W);
                const int c2 = __shfl(E.x, j + 2, W), c3 = __shfl(E.x, j + 3, W);
                const int c4 = __shfl(E.x, j + 4, W), c5 = __shfl(E.x, j + 5, W);
                const int c6 = __shfl(E.x, j + 6, W), c7 = __shfl(E.x, j + 7, W);
                const int v0 = __shfl(E.y, j + 0, W), v1 = __shfl(E.y, j + 1, W);
                const int v2 = __shfl(E.y, j + 2, W), v3 = __shfl(E.y, j + 3, W);
                const int v4 = __shfl(E.y, j + 4, W), v5 = __shfl(E.y, j + 5, W);
                const int v6 = __shfl(E.y, j + 6, W), v7 = __shfl(E.y, j + 7, W);
                const f32x4 x0v = *(const f32x4*)(xf + ((size_t)c0 << cshf));
                const f32x4 x1v = *(const f32x4*)(xf + ((size_t)c1 << cshf));
                const f32x4 x2v = *(const f32x4*)(xf + ((size_t)c2 << cshf));
                const f32x4 x3v = *(const f32x4*)(xf + ((size_t)c3 << cshf));
                const f32x4 x4v = *(const f32x4*)(xf + ((size_t)c4 << cshf));
                const f32x4 x5v = *(const f32x4*)(xf + ((size_t)c5 << cshf));
                const f32x4 x6v = *(const f32x4*)(xf + ((size_t)c6 << cshf));
                const f32x4 x7v = *(const f32x4*)(xf + ((size_t)c7 << cshf));
                a0 = fma4(__int_as_float(v0), x0v, a0);
                a1 = fma4(__int_as_float(v1), x1v, a1);
                a2 = fma4(__int_as_float(v2), x2v, a2);
                a3 = fma4(__int_as_float(v3), x3v, a3);
                a0 = fma4(__int_as_float(v4), x4v, a0);
                a1 = fma4(__int_as_float(v5), x5v, a1);
                a2 = fma4(__int_as_float(v6), x6v, a2);
                a3 = fma4(__int_as_float(v7), x7v, a3);
            }
            for (; j + 2 <= n2; j += 2) {
                const int c0 = __shfl(E.x, j, W), v0 = __shfl(E.y, j, W);
                const int c1 = __shfl(E.x, j + 1, W), v1 = __shfl(E.y, j + 1, W);
                const f32x4 x0v = *(const f32x4*)(xf + ((size_t)c0 << cshf));
                const f32x4 x1v = *(const f32x4*)(xf + ((size_t)c1 << cshf));
                a0 = fma4(__int_as_float(v0), x0v, a0);
                a1 = fma4(__int_as_float(v1), x1v, a1);
            }
            if (j < n2) {
                const int c0 = __shfl(E.x, j, W), v0 = __shfl(E.y, j, W);
                const f32x4 x0v = *(const f32x4*)(xf + ((size_t)c0 << cshf));
                a0 = fma4(__int_as_float(v0), x0v, a0);
            }
        } else {
            for (; j + 8 <= n2; j += 8) {
                const int c0 = __shfl(E.x, j + 0, W), c1 = __shfl(E.x, j + 1, W);
                const int c2 = __shfl(E.x, j + 2, W), c3 = __shfl(E.x, j + 3, W);
                const int c4 = __shfl(E.x, j + 4, W), c5 = __shfl(E.x, j + 5, W);
                const int c6 = __shfl(E.x, j + 6, W), c7 = __shfl(E.x, j + 7, W);
                const int v0 = __shfl(E.y, j + 0, W), v1 = __shfl(E.y, j + 1, W);
                const int v2 = __shfl(E.y, j + 2, W), v3 = __shfl(E.y, j + 3, W);
                const int v4 = __shfl(E.y, j + 4, W), v5 = __shfl(E.y, j + 5, W);
                const int v6 = __shfl(E.y, j + 6, W), v7 = __shfl(E.y, j + 7, W);
                const uint2 u0 = *(const uint2*)(xu + ((size_t)c0 << cshu));
                const uint2 u1 = *(const uint2*)(xu + ((size_t)c1 << cshu));
                const uint2 u2 = *(const uint2*)(xu + ((size_t)c2 << cshu));
                const uint2 u3 = *(const uint2*)(xu + ((size_t)c3 << cshu));
                const uint2 u4 = *(const uint2*)(xu + ((size_t)c4 << cshu));
                const uint2 u5 = *(const uint2*)(xu + ((size_t)c5 << cshu));
                const uint2 u6 = *(const uint2*)(xu + ((size_t)c6 << cshu));
                const uint2 u7 = *(const uint2*)(xu + ((size_t)c7 << cshu));
                a0 = fma4p(__int_as_float(v0), u0, a0);
                a1 = fma4p(__int_as_float(v1), u1, a1);
                a2 = fma4p(__int_as_float(v2), u2, a2);
                a3 = fma4p(__int_as_float(v3), u3, a3);
                a0 = fma4p(__int_as_float(v4), u4, a0);
                a1 = fma4p(__int_as_float(v5), u5, a1);
                a2 = fma4p(__int_as_float(v6), u6, a2);
                a3 = fma4p(__int_as_float(v7), u7, a3);
            }
            for (; j + 2 <= n2; j += 2) {
                const int c0 = __shfl(E.x, j, W), v0 = __shfl(E.y, j, W);
                const int c1 = __shfl(E.x, j + 1, W), v1 = __shfl(E.y, j + 1, W);
                const uint2 u0 = *(const uint2*)(xu + ((size_t)c0 << cshu));
                const uint2 u1 = *(const uint2*)(xu + ((size_t)c1 << cshu));
                a0 = fma4p(__int_as_float(v0), u0, a0);
                a1 = fma4p(__int_as_float(v1), u1, a1);
            }
            if (j < n2) {
                const int c0 = __shfl(E.x, j, W), v0 = __shfl(E.y, j, W);
                const uint2 u0 = *(const uint2*)(xu + ((size_t)c0 << cshu));
                a0 = fma4p(__int_as_float(v0), u0, a0);
            }
        }
    }
    f32x4 R;
    R.x = (a0.x + a1.x) + (a2.x + a3.x);
    R.y = (a0.y + a1.y) + (a2.y + a3.y);
    R.z = (a0.z + a1.z) + (a2.z + a3.z);
    R.w = (a0.w + a1.w) + (a2.w + a3.w);

    if (MODE) {
        const f32x4 pv = *(const f32x4*)(pb + ((size_t)r << psh));
        R.x = 2.0f * R.x - pv.x; R.y = 2.0f * R.y - pv.y;
        R.z = 2.0f * R.z - pv.z; R.w = 2.0f * R.w - pv.w;
    }
    uint2 o2;
    o2.x = pkhi2(R.x, R.y); o2.y = pkhi2(R.z, R.w);
    *(uint2*)(dstu + (size_t)r * drow) = o2;
}

// ------ mm staging: m=0 f32 -> pack; m=1..4 pre-packed copy -----------------
template<int NT>
__device__ __forceinline__ void stage_hi(const float* __restrict__ xs, const float* __restrict__ xi,
                                         const float* __restrict__ m0s, int m0hx,
                                         int n, int tid, uint* __restrict__ Bhi)
{
    for (int i = tid; i < 480; i += NT) {       // zero K-pad words 165..179 per b-row
        int bl = i / 15, t = i - bl * 15;
        Bhi[bl * 180 + 165 + t] = 0u;
    }
    for (int i = tid; i < 2560; i += NT) {      // state: 5 m x 32 bl x 16 quads
        int m = i >> 9, rem = i & 511, bl = rem >> 4, fq = rem & 15;
        const int base = bl * 180 + m * 33 + 1 + fq * 2;
        if (m == 0) {
            const float* p = m0hx ? m0s + (size_t)bl * 262144 + (size_t)n * 64 + fq * 4
                                  : m0s + (size_t)n * SROW + bl * 64 + fq * 4;
            const f32x4 v = *(const f32x4*)p;
            Bhi[base]     = pkhi2(v.x, v.y);
            Bhi[base + 1] = pkhi2(v.z, v.w);
        } else {
            const uint* xp = (const uint*)(xs + (size_t)m * SLVL);
            const uint2 u = *(const uint2*)(xp + (size_t)n * 1024 + bl * 32 + fq * 2);
            Bhi[base]     = u.x;
            Bhi[base + 1] = u.y;
        }
    }
    for (int i = tid; i < 160; i += NT) {       // input: 5 m x 32 bl
        int m = i >> 5, bl = i & 31;
        if (m == 0) {
            const f32x2 v = *(const f32x2*)(xi + (size_t)n * IROW + bl * 2);
            Bhi[bl * 180] = pkhi2(v.x, v.y);
        } else {
            const uint* xp = (const uint*)(xi + (size_t)m * ILVL);
            Bhi[bl * 180 + m * 33] = xp[(size_t)n * 32 + bl];
        }
    }
}

#define MFMA(a, b, c) __builtin_amdgcn_mfma_f32_16x16x32_bf16(a, b, c, 0, 0, 0)

// -------- gconv1 matmul (round-12 proven config): 8 nodes/block, 8 waves ----
__global__ __launch_bounds__(512, 4) void mm_ru_k(const float* __restrict__ xs, const float* __restrict__ xi,
                                                  const ushort* __restrict__ whi, const ushort* __restrict__ wlo,
                                                  const float* __restrict__ bru, const float* __restrict__ hx,
                                                  float* __restrict__ uout, float* __restrict__ xs0s, int h)
{
    const int tid = threadIdx.x;
    const int lane = tid & 63, wave = tid >> 6;
    __shared__ uint Bbuf[2][5760];
    const int n0 = blockIdx.x * NPB;
    const float* hxs = hx + (size_t)h * HB * 262144;

    const int ob = wave * 16 + (lane & 15);
    const int ksub = (lane >> 4) * 8;
    const int brow = lane & 15;
    short8 Ah[KSTEPS], Al[KSTEPS];
    #pragma unroll
    for (int ks = 0; ks < KSTEPS; ++ks) {
        Ah[ks] = *(const short8*)(whi + (size_t)ob * KP + ks * 32 + ksub);
        Al[ks] = *(const short8*)(wlo + (size_t)ob * KP + ks * 32 + ksub);
    }
    const int g = lane >> 4, bcol = lane & 15;
    const int o = wave * 16 + g * 4;
    const float bb0 = bru[o], bb1 = bru[o + 1], bb2 = bru[o + 2], bb3 = bru[o + 3];

    stage_hi<512>(xs, xi, hxs, 1, n0, tid, Bbuf[0]);

    for (int i = 0; i < NPB; ++i) {
        __syncthreads();
        if (i + 1 < NPB)
            stage_hi<512>(xs, xi, hxs, 1, n0 + i + 1, tid, Bbuf[(i + 1) & 1]);
        const ushort* BH = (const ushort*)Bbuf[i & 1];
        const int n = n0 + i;
        f32x4 acc[2] = {};
        #pragma unroll
        for (int ks = 0; ks < KSTEPS; ++ks) {
            const int ko = ks * 32 + ksub;
            short8 Bh0 = *(const short8*)(BH + brow * 360 + ko);
            short8 Bh1 = *(const short8*)(BH + (16 + brow) * 360 + ko);
            acc[0] = MFMA(Ah[ks], Bh0, acc[0]);
            acc[1] = MFMA(Ah[ks], Bh1, acc[1]);
            acc[0] = MFMA(Al[ks], Bh0, acc[0]);
            acc[1] = MFMA(Al[ks], Bh1, acc[1]);
        }
        #pragma unroll
        for (int bt = 0; bt < 2; ++bt) {
            const int bl = bt * 16 + bcol;
            float s0 = sigm(acc[bt][0] + bb0);
            float s1 = sigm(acc[bt][1] + bb1);
            float s2 = sigm(acc[bt][2] + bb2);
            float s3 = sigm(acc[bt][3] + bb3);
            if (wave < 4) {     // r-part: r*hx -> x0 state
                const f32x4 hxv = *(const f32x4*)(hx + (size_t)(h * HB + bl) * 262144 + (size_t)n * 64 + o);
                f32x4 rv;
                rv[0] = s0 * hxv[0]; rv[1] = s1 * hxv[1];
                rv[2] = s2 * hxv[2]; rv[3] = s3 * hxv[3];
                *(f32x4*)(xs0s + (size_t)n * SROW + bl * 64 + o) = rv;
            } else {            // u-part -> d_out (temporary storage)
                f32x4 uv = {s0, s1, s2, s3};
                *(f32x4*)(uout + (size_t)(h * HB + bl) * 262144 + (size_t)n * 64 + (o - 64)) = uv;
            }
        }
    }
}

// -------- gconv2 matmul: 8 nodes/block, 4 waves (round-12 config) -----------
__global__ __launch_bounds__(256, 4) void mm_c_k(const float* __restrict__ xs, const float* __restrict__ xi,
                                                 const ushort* __restrict__ whi, const ushort* __restrict__ wlo,
                                                 const float* __restrict__ bc, const float* __restrict__ hx,
                                                 float* __restrict__ out, int h)
{
    const int tid = threadIdx.x;
    const int lane = tid & 63, wave = tid >> 6;
    __shared__ uint Bbuf[2][5760];
    const int n0 = blockIdx.x * NPB;

    const int ob = wave * 16 + (lane & 15);
    const int ksub = (lane >> 4) * 8;
    const int brow = lane & 15;
    short8 Ah[KSTEPS], Al[KSTEPS];
    #pragma unroll
    for (int ks = 0; ks < KSTEPS; ++ks) {
        Ah[ks] = *(const short8*)(whi + (size_t)ob * KP + ks * 32 + ksub);
        Al[ks] = *(const short8*)(wlo + (size_t)ob * KP + ks * 32 + ksub);
    }
    const int g = lane >> 4, bcol = lane & 15;
    const int o = wave * 16 + g * 4;
    const float bb0 = bc[o], bb1 = bc[o + 1], bb2 = bc[o + 2], bb3 = bc[o + 3];

    stage_hi<256>(xs, xi, xs, 0, n0, tid, Bbuf[0]);

    for (int i = 0; i < NPB; ++i) {
        __syncthreads();
        if (i + 1 < NPB)
            stage_hi<256>(xs, xi, xs, 0, n0 + i + 1, tid, Bbuf[(i + 1) & 1]);
        const ushort* BH = (const ushort*)Bbuf[i & 1];
        const int n = n0 + i;
        f32x4 acc[2] = {};
        #pragma unroll
        for (int ks = 0; ks < KSTEPS; ++ks) {
            const int ko = ks * 32 + ksub;
            short8 Bh0 = *(const short8*)(BH + brow * 360 + ko);
            short8 Bh1 = *(const short8*)(BH + (16 + brow) * 360 + ko);
            acc[0] = MFMA(Ah[ks], Bh0, acc[0]);
            acc[1] = MFMA(Ah[ks], Bh1, acc[1]);
            acc[0] = MFMA(Al[ks], Bh0, acc[0]);
            acc[1] = MFMA(Al[ks], Bh1, acc[1]);
        }
        #pragma unroll
        for (int bt = 0; bt < 2; ++bt) {
            const int bl = bt * 16 + bcol;
            float c0 = tanh_fast(acc[bt][0] + bb0);
            float c1 = tanh_fast(acc[bt][1] + bb1);
            float c2 = tanh_fast(acc[bt][2] + bb2);
            float c3 = tanh_fast(acc[bt][3] + bb3);
            float* p = out + (size_t)(h * HB + bl) * 262144 + (size_t)n * 64 + o;
            const f32x4 hxv = *(const f32x4*)(hx + (size_t)(h * HB + bl) * 262144 + (size_t)n * 64 + o);
            f32x4 uv = *(const f32x4*)p;
            f32x4 ov;
            ov[0] = uv[0] * hxv[0] + (1.0f - uv[0]) * c0;
            ov[1] = uv[1] * hxv[1] + (1.0f - uv[1]) * c1;
            ov[2] = uv[2] * hxv[2] + (1.0f - uv[2]) * c2;
            ov[3] = uv[3] * hxv[3] + (1.0f - uv[3]) * c3;
            *(f32x4*)p = ov;
        }
    }
}

// ---------------------------------------------------------------------------
extern "C" void kernel_launch(void* const* d_in, const int* in_sizes, int n_in,
                              void* d_out, int out_size, void* d_ws, size_t ws_size,
                              hipStream_t stream)
{
    (void)in_sizes; (void)n_in; (void)out_size; (void)ws_size;
    const float* inputs  = (const float*)d_in[0];
    const float* hx      = (const float*)d_in[1];
    const int*   sup_rows= (const int*)d_in[2];
    const int*   sup_cols= (const int*)d_in[3];
    const float* sup_vals= (const float*)d_in[4];
    const float* W_ru    = (const float*)d_in[5];
    const float* b_ru    = (const float*)d_in[6];
    const float* W_c     = (const float*)d_in[7];
    const float* b_c     = (const float*)d_in[8];
    float* out = (float*)d_out;

    char* ws = (char*)d_ws;
    float* xs = (float*)ws;                                 // level 0 f32; levels 1-4 packed bf16
    float* xi = xs + 5ull * SLVL;
    size_t off = (5ull * SLVL + 5ull * ILVL) * 4ull;        // 173,015,040
    ushort* wru_hi = (ushort*)(ws + off); off += 90112;
    ushort* wru_lo = (ushort*)(ws + off); off += 90112;
    ushort* wc_hi  = (ushort*)(ws + off); off += 45056;
    ushort* wc_lo  = (ushort*)(ws + off); off += 45056;
    int* row_ptr   = (int*)(ws + off);    off += 32800;
    int* cntfill   = (int*)(ws + off);    off += 65536;
    int2* pcv      = (int2*)(ws + off);   off += 1048576;   // packed (col,val) CSR

    #define XS(m) (xs + (size_t)(m) * SLVL)
    #define XI(m) (xi + (size_t)(m) * ILVL)
    int* fill = cntfill + 8192;

    zero_k<<<64, 256, 0, stream>>>(cntfill);
    wtbuild_k<<<264, 256, 0, stream>>>(W_ru, W_c, wru_hi, wru_lo, wc_hi, wc_lo);
    count_k<<<512, 256, 0, stream>>>(sup_rows, cntfill);
    scan_k<<<2, 1024, 0, stream>>>(cntfill, row_ptr);
    scatter_k<<<512, 256, 0, stream>>>(sup_rows, sup_cols, sup_vals, row_ptr, fill, pcv);

    for (int h = 0; h < 2; ++h) {
        const float* hxs = hx + (size_t)h * HB * 262144;
        x0i_k<<<512, 256, 0, stream>>>(inputs, XI(0), h);
        // gconv1 diffusion: step1 reads hx in place, writes packed x1/x3;
        // step2 gathers packed, prev = hx (hxpm)
        spmm_k<0><<<dim3(8448, 2), 256, 0, stream>>>(hxs, XI(0), hxs, XI(0),
                                                     XS(1), XI(1), XS(3), XI(3),
                                                     hxs, XI(0), row_ptr, pcv, 1, 0);
        spmm_k<1><<<dim3(16896, 1), 256, 0, stream>>>(XS(1), XI(1), XS(3), XI(3),
                                                      XS(2), XI(2), XS(4), XI(4),
                                                      hxs, XI(0), row_ptr, pcv, 0, 1);
        // gconv1 matmul: u -> out, r*hx -> x0 state part (m0 staged from hx)
        mm_ru_k<<<NN / NPB, 512, 0, stream>>>(xs, xi, wru_hi, wru_lo, b_ru, hx, out, XS(0), h);
        // gconv2 diffusion (x0 = [inputs, r*hx] f32; chain packed)
        spmm_k<0><<<dim3(8448, 2), 256, 0, stream>>>(XS(0), XI(0), XS(0), XI(0),
                                                     XS(1), XI(1), XS(3), XI(3),
                                                     XS(0), XI(0), row_ptr, pcv, 0, 0);
        spmm_k<1><<<dim3(16896, 1), 256, 0, stream>>>(XS(1), XI(1), XS(3), XI(3),
                                                      XS(2), XI(2), XS(4), XI(4),
                                                      XS(0), XI(0), row_ptr, pcv, 0, 0);
        // gconv2 matmul + tanh + final GRU combine
        mm_c_k<<<NN / NPB, 256, 0, stream>>>(xs, xi, wc_hi, wc_lo, b_c, hx, out, h);
    }
    #undef XS
    #undef XI
}